// Round 6
// baseline (420.009 us; speedup 1.0000x reference)
//
#include <hip/hip_runtime.h>
#include <hip/hip_cooperative_groups.h>
#include <math.h>

namespace cg = cooperative_groups;

#define N_PTS   131072
#define EPOCHS  1000
#define EPAD    1024
#define THRESH2 100.0f   // dis <= 10  <=>  dis^2 <= 100

#define NB 512           // blocks (2 per CU, fully resident)
#define NT 256           // threads per block (4 waves); NB*NT == N_PTS

// ---------------- workspace layout (bytes) ----------------
// H       float4[1024]        @ 0       (16384)
// counts  int[1024]           @ 16384   (4096)
// best    float4              @ 20480   (16)
// rpart   float[512][16]      @ 20496   (32768)  -> ends 53264
// partial ushort[512][1024]   @ 65536   (1048576) -> ends 1114112
#define OFF_COUNTS  16384
#define OFF_BEST    20480
#define OFF_RPART   20496
#define OFF_PARTIAL 65536

// Evaluate hypothesis h against this thread's point; ballot the wave's 64
// inlier bools -> wave-uniform popcount pc; lane SLOT keeps pc in cnt_v.
// (SLOT is compile-time 0..63; compiles to v_cmp_eq + v_cndmask.)
#define EVALH(h, SLOT)                                                      \
    {                                                                       \
        float ex = fmaf(-(h).x, ax, fmaf((h).y, ay, bx - (h).z));           \
        float ey = fmaf(-(h).y, ax, fmaf(-(h).x, ay, by - (h).w));          \
        float d2 = fmaf(ex, ex, ey * ey);                                   \
        unsigned long long mm = __ballot(d2 <= THRESH2);                    \
        int pc = (int)__popcll(mm);                                         \
        cnt_v = (lane == (SLOT)) ? pc : cnt_v;                              \
    }

__global__ __launch_bounds__(NT) void ransac_mega(
        const float* __restrict__ A, const float* __restrict__ B,
        const int* __restrict__ sub, float* __restrict__ out,
        char* __restrict__ ws) {
    float4*         H       = (float4*)(ws);
    int*            counts  = (int*)(ws + OFF_COUNTS);
    float4*         best    = (float4*)(ws + OFF_BEST);
    float*          rpart   = (float*)(ws + OFF_RPART);
    unsigned short* partial = (unsigned short*)(ws + OFF_PARTIAL);

    __shared__ unsigned lcnt[4][1024];     // 16KB: per-wave hyp counts; reused in P3
    __shared__ int scnt[256], sidxs[256];  // 2KB: argmax scratch (block 0)

    cg::grid_group grid = cg::this_grid();
    int tid  = threadIdx.x;
    int bid  = blockIdx.x;
    int gid  = bid * NT + tid;
    int wave = tid >> 6, lane = tid & 63;

    // ---------------- P0: hypotheses + init ----------------
    if (gid < EPAD) {
        counts[gid] = 0;
        if (gid < EPOCHS) {
            float pax[5], pay[5], pbx[5], pby[5];
            float cAx = 0.f, cAy = 0.f, cBx = 0.f, cBy = 0.f;
#pragma unroll
            for (int j = 0; j < 5; ++j) {
                int p = sub[gid * 5 + j];
                pax[j] = A[2 * p];     pay[j] = A[2 * p + 1];
                pbx[j] = B[2 * p];     pby[j] = B[2 * p + 1];
                cAx += pax[j]; cAy += pay[j];
                cBx += pbx[j]; cBy += pby[j];
            }
            cAx *= 0.2f; cAy *= 0.2f; cBx *= 0.2f; cBy *= 0.2f;
            float sxx = 0.f, sxy = 0.f;
#pragma unroll
            for (int j = 0; j < 5; ++j) {
                float a0x = pax[j] - cAx, a0y = pay[j] - cAy;
                float b0x = pbx[j] - cBx, b0y = pby[j] - cBy;
                sxx += a0x * b0x + a0y * b0y;
                sxy += a0x * b0y - a0y * b0x;
            }
            float rot = atan2f(sxy, sxx);
            float s, c;
            sincosf(rot, &s, &c);
            float u = cBx - (c * cAx - s * cAy);
            float v = cBy - (s * cAx + c * cAy);
            H[gid] = make_float4(c, s, u, v);
        } else {
            H[gid] = make_float4(1.f, 0.f, 0.f, 0.f);  // masked at argmax anyway
        }
    }

    // this thread's point — lives in registers through P1 AND P3
    float2 a2 = ((const float2*)A)[gid];
    float2 b2 = ((const float2*)B)[gid];
    float ax = a2.x, ay = a2.y, bx = b2.x, by = b2.y;

    grid.sync();

    // ---------------- P1: score (thread = point, loop over hyps) ----------------
    {
        float4 bufA[8], bufB[8];
#pragma unroll
        for (int j = 0; j < 8; ++j) bufA[j] = H[j];   // group 0
        int cnt_v = 0;
        for (int sg = 0; sg < 16; ++sg) {             // 16 super-groups of 64 hyps
#pragma unroll
            for (int gg = 0; gg < 8; ++gg) {          // 8 groups of 8, ping-pong
                int g = sg * 8 + gg;
                if (gg & 1) {
#pragma unroll
                    for (int j = 0; j < 8; ++j) bufA[j] = H[(g + 1) * 8 + j];
                    EVALH(bufB[0], gg * 8 + 0); EVALH(bufB[1], gg * 8 + 1);
                    EVALH(bufB[2], gg * 8 + 2); EVALH(bufB[3], gg * 8 + 3);
                    EVALH(bufB[4], gg * 8 + 4); EVALH(bufB[5], gg * 8 + 5);
                    EVALH(bufB[6], gg * 8 + 6); EVALH(bufB[7], gg * 8 + 7);
                } else {
#pragma unroll
                    for (int j = 0; j < 8; ++j) bufB[j] = H[(g + 1) * 8 + j];
                    EVALH(bufA[0], gg * 8 + 0); EVALH(bufA[1], gg * 8 + 1);
                    EVALH(bufA[2], gg * 8 + 2); EVALH(bufA[3], gg * 8 + 3);
                    EVALH(bufA[4], gg * 8 + 4); EVALH(bufA[5], gg * 8 + 5);
                    EVALH(bufA[6], gg * 8 + 6); EVALH(bufA[7], gg * 8 + 7);
                }
            }
            // lane k of cnt_v holds wave's count for hyp sg*64+k
            lcnt[wave][sg * 64 + lane] = (unsigned)cnt_v;
            cnt_v = 0;
        }
        // (final prefetch reads H[1024..1031] == counts area — unused, in-bounds)
        __syncthreads();
#pragma unroll
        for (int k = 0; k < 4; ++k) {
            int e = tid + k * 256;
            unsigned s0 = lcnt[0][e] + lcnt[1][e] + lcnt[2][e] + lcnt[3][e];
            partial[bid * EPAD + e] = (unsigned short)s0;   // block count <= 256
        }
    }

    grid.sync();

    // ---------------- P2a: counts[e] = sum over 512 blocks (64 blocks x 8 rows) ----
    if (bid < 64) {
#pragma unroll
        for (int k = 0; k < 4; ++k) {
            int e = tid + k * 256;
            int ssum = 0;
#pragma unroll
            for (int r = 0; r < 8; ++r) ssum += partial[(bid * 8 + r) * EPAD + e];
            atomicAdd(&counts[e], ssum);                    // int: order-independent
        }
    }

    grid.sync();

    // ---------------- P2b: argmax (block 0, first-index tie-break == jnp.argmax) ----
    if (bid == 0) {
        int bc = -1, bi = 0;
        for (int e = tid; e < EPAD; e += 256) {             // ascending: '>' keeps first
            int cv = (e < EPOCHS) ? counts[e] : -1;         // mask padded hyps
            if (cv > bc) { bc = cv; bi = e; }
        }
        scnt[tid] = bc; sidxs[tid] = bi;
        __syncthreads();
        for (int s2 = 128; s2 > 0; s2 >>= 1) {
            if (tid < s2) {
                int c2 = scnt[tid + s2], i2 = sidxs[tid + s2];
                if (c2 > scnt[tid] || (c2 == scnt[tid] && i2 < sidxs[tid])) {
                    scnt[tid] = c2; sidxs[tid] = i2;
                }
            }
            __syncthreads();
        }
        if (tid == 0) {
            float4 h = H[sidxs[0]];
            *best = h;
            out[9]  = h.x;  out[10] = -h.y; out[11] = h.z;
            out[12] = h.y;  out[13] = h.x;  out[14] = h.w;
            out[15] = 0.f;  out[16] = 0.f;  out[17] = 1.f;
        }
    }

    grid.sync();

    // ---------------- P3: refit moments (point still in registers) ----------------
    {
        float4 h = *best;
        float ex = fmaf(-h.x, ax, fmaf(h.y, ay, bx - h.z));
        float ey = fmaf(-h.y, ax, fmaf(-h.x, ay, by - h.w));
        float d2 = fmaf(ex, ex, ey * ey);
        bool w = (d2 <= THRESH2);
        float m[9];
        m[0] = w ? 1.f : 0.f;
        m[1] = w ? ax : 0.f;        m[2] = w ? ay : 0.f;
        m[3] = w ? bx : 0.f;        m[4] = w ? by : 0.f;
        m[5] = w ? ax * bx : 0.f;   m[6] = w ? ax * by : 0.f;
        m[7] = w ? ay * bx : 0.f;   m[8] = w ? ay * by : 0.f;
#pragma unroll
        for (int off = 32; off > 0; off >>= 1)
#pragma unroll
            for (int j = 0; j < 9; ++j) m[j] += __shfl_down(m[j], off);
        float* fred = (float*)lcnt;                     // reuse LDS
        if (lane == 0)
#pragma unroll
            for (int j = 0; j < 9; ++j) fred[wave * 16 + j] = m[j];
        __syncthreads();
        if (tid == 0)
#pragma unroll
            for (int j = 0; j < 9; ++j)
                rpart[bid * 16 + j] = fred[j] + fred[16 + j] + fred[32 + j] + fred[48 + j];
    }

    grid.sync();

    // ---------------- P4: final reduce + E_final (block 0, wave 0) ----------------
    if (bid == 0 && tid < 64) {
        float m[9];
#pragma unroll
        for (int j = 0; j < 9; ++j) m[j] = 0.f;
        for (int r = tid; r < NB; r += 64)              // 8 rows per lane
#pragma unroll
            for (int j = 0; j < 9; ++j) m[j] += rpart[r * 16 + j];
#pragma unroll
        for (int off = 32; off > 0; off >>= 1)
#pragma unroll
            for (int j = 0; j < 9; ++j) m[j] += __shfl_down(m[j], off);
        if (tid == 0) {
            float wsum = fmaxf(m[0], 1e-8f);
            float cAx = m[1] / wsum, cAy = m[2] / wsum;
            float cBx = m[3] / wsum, cBy = m[4] / wsum;
            float sxx = (m[5] - wsum * cAx * cBx) + (m[8] - wsum * cAy * cBy);
            float sxy = (m[6] - wsum * cAx * cBy) - (m[7] - wsum * cAy * cBx);
            float rot = atan2f(sxy, sxx);
            float s, c;
            sincosf(rot, &s, &c);
            float u = cBx - (c * cAx - s * cAy);
            float v = cBy - (s * cAx + c * cAy);
            out[0] = c;   out[1] = -s;  out[2] = u;
            out[3] = s;   out[4] = c;   out[5] = v;
            out[6] = 0.f; out[7] = 0.f; out[8] = 1.f;
        }
    }
}

extern "C" void kernel_launch(void* const* d_in, const int* in_sizes, int n_in,
                              void* d_out, int out_size, void* d_ws, size_t ws_size,
                              hipStream_t stream) {
    const float* A  = (const float*)d_in[0];   // pstA [1,N,2]
    const float* B  = (const float*)d_in[1];   // pstB [1,N,2]
    const int* sidx = (const int*)d_in[2];     // subset_idx [EPOCHS,5]
    float* out = (float*)d_out;
    char* ws = (char*)d_ws;

    void* args[] = {(void*)&A, (void*)&B, (void*)&sidx, (void*)&out, (void*)&ws};
    (void)hipLaunchCooperativeKernel((const void*)ransac_mega, dim3(NB), dim3(NT),
                                     args, 0, stream);
}

// Round 7
// 155.001 us; speedup vs baseline: 2.7097x; 2.7097x over previous
//
#include <hip/hip_runtime.h>
#include <math.h>

#define N_PTS   131072
#define EPOCHS  1000
#define EPAD    1024
#define THRESH2 100.0f   // dis <= 10  <=>  dis^2 <= 100

#define SC_BLOCKS  1024
#define SC_NT      256                     // 4 hyps per thread
#define SC_PTS     (N_PTS / SC_BLOCKS)     // 128 points per block

#define RF_BLOCKS  256
#define RF_THREADS 256                     // 2 points (1 float4) per thread

// ---------------- workspace layout (bytes) ----------------
// H        float4[1024]          @ 0         (16384)
// partial  u8[1024][1024]        @ 16384     (1048576) -> 1064960
// partial2 int[8][1024]          @ 1064960   (32768)   -> 1097728
// best     float4                @ 1097728   (16)      -> 1097744
// rpart    float[256][16]        @ 1097744   (16384)   -> 1114128 (proven size)
#define OFF_H        0
#define OFF_PARTIAL  16384
#define OFF_PARTIAL2 1064960
#define OFF_BEST     1097728
#define OFF_RPART    1097744

// Kernel 1: one thread per epoch — 5-point rigid fit.
__global__ void hypo_kernel(const float* __restrict__ A, const float* __restrict__ B,
                            const int* __restrict__ idx, float4* __restrict__ H) {
    int e = blockIdx.x * blockDim.x + threadIdx.x;
    if (e >= EPOCHS) return;

    float ax[5], ay[5], bx[5], by[5];
    float cAx = 0.f, cAy = 0.f, cBx = 0.f, cBy = 0.f;
#pragma unroll
    for (int j = 0; j < 5; ++j) {
        int p = idx[e * 5 + j];
        ax[j] = A[2 * p];     ay[j] = A[2 * p + 1];
        bx[j] = B[2 * p];     by[j] = B[2 * p + 1];
        cAx += ax[j]; cAy += ay[j];
        cBx += bx[j]; cBy += by[j];
    }
    cAx *= 0.2f; cAy *= 0.2f; cBx *= 0.2f; cBy *= 0.2f;

    float sxx = 0.f, sxy = 0.f;
#pragma unroll
    for (int j = 0; j < 5; ++j) {
        float a0x = ax[j] - cAx, a0y = ay[j] - cAy;
        float b0x = bx[j] - cBx, b0y = by[j] - cBy;
        sxx += a0x * b0x + a0y * b0y;
        sxy += a0x * b0y - a0y * b0x;
    }
    float rot = atan2f(sxy, sxx);
    float s, c;
    sincosf(rot, &s, &c);
    float u = cBx - (c * cAx - s * cAy);
    float v = cBy - (s * cAx + c * cAy);
    H[e] = make_float4(c, s, u, v);
}

// Kernel 2: scoring. Block = 128-point chunk (LDS-staged), thread = 4 hypotheses.
#define EVAL(h, cnt)                                                        \
    {                                                                       \
        float ex = fmaf(-(h).x, p.x, fmaf((h).y, p.y, p.z - (h).z));        \
        float ey = fmaf(-(h).y, p.x, fmaf(-(h).x, p.y, p.w - (h).w));       \
        float d2 = fmaf(ex, ex, ey * ey);                                   \
        cnt += (d2 <= THRESH2) ? 1 : 0;                                     \
    }

__global__ __launch_bounds__(SC_NT, 8) void score_kernel(
        const float* __restrict__ A, const float* __restrict__ B,
        const float4* __restrict__ H, unsigned char* __restrict__ partial) {
    __shared__ float4 pts[SC_PTS];         // 2 KB: (ax,ay,bx,by) per point
    int tid = threadIdx.x;
    int bid = blockIdx.x;

    if (tid < SC_PTS) {
        float2 a = ((const float2*)A)[bid * SC_PTS + tid];
        float2 b = ((const float2*)B)[bid * SC_PTS + tid];
        pts[tid] = make_float4(a.x, a.y, b.x, b.y);
    }
    float4 h0 = H[tid];                    // hyps t, t+256, t+512, t+768
    float4 h1 = H[tid + 256];
    float4 h2 = H[tid + 512];
    float4 h3 = H[tid + 768];
    __syncthreads();

    int c0 = 0, c1 = 0, c2 = 0, c3 = 0;
#pragma unroll 4
    for (int k = 0; k < SC_PTS; ++k) {
        float4 p = pts[k];                 // uniform addr -> LDS broadcast
        EVAL(h0, c0); EVAL(h1, c1); EVAL(h2, c2); EVAL(h3, c3);
    }
    unsigned char* row = partial + bid * EPAD;
    row[tid]       = (unsigned char)c0;    // counts <= 128
    row[tid + 256] = (unsigned char)c1;
    row[tid + 512] = (unsigned char)c2;
    row[tid + 768] = (unsigned char)c3;
}

// Kernel 3: stage-A count reduction: 8 groups of 128 chunk-rows each.
__global__ void reduce_counts_kernel(const unsigned char* __restrict__ partial,
                                     int* __restrict__ partial2) {
    int gid = blockIdx.x * blockDim.x + threadIdx.x;   // 8192 threads
    int e = gid & (EPAD - 1);
    int g = gid >> 10;                                 // 0..7
    int s = 0;
    int base = g * 128;
#pragma unroll 8
    for (int k = 0; k < 128; ++k) s += partial[(base + k) * EPAD + e];
    partial2[g * EPAD + e] = s;
}

// Kernel 4: final count sum + argmax (first-index tie-break == jnp.argmax),
// emit E_best, stash best params.
__global__ void argmax_kernel(const int* __restrict__ partial2, const float4* __restrict__ H,
                              float* __restrict__ out, float4* __restrict__ best) {
    __shared__ int scnt[256];
    __shared__ int sidx[256];
    int tid = threadIdx.x;
    int bc = -2, bi = 0;
    for (int e = tid; e < EPAD; e += 256) {            // ascending: '>' keeps first max
        int cv = -1;
        if (e < EPOCHS) {
            cv = 0;
#pragma unroll
            for (int g = 0; g < 8; ++g) cv += partial2[g * EPAD + e];
        }
        if (cv > bc) { bc = cv; bi = e; }
    }
    scnt[tid] = bc; sidx[tid] = bi;
    __syncthreads();
    for (int s2 = 128; s2 > 0; s2 >>= 1) {
        if (tid < s2) {
            int c2 = scnt[tid + s2], i2 = sidx[tid + s2];
            if (c2 > scnt[tid] || (c2 == scnt[tid] && i2 < sidx[tid])) {
                scnt[tid] = c2; sidx[tid] = i2;
            }
        }
        __syncthreads();
    }
    if (tid == 0) {
        float4 h = H[sidx[0]];
        *best = h;
        out[9]  = h.x;  out[10] = -h.y; out[11] = h.z;
        out[12] = h.y;  out[13] = h.x;  out[14] = h.w;
        out[15] = 0.f;  out[16] = 0.f;  out[17] = 1.f;
    }
}

// Kernel 5: refit raw moments; 2 points (one float4) per thread; no atomics.
//  moments: 0=Sw 1=SxA 2=SyA 3=SxB 4=SyB 5=SxAxB 6=SxAyB 7=SyAxB 8=SyAyB
__global__ __launch_bounds__(RF_THREADS) void refit_kernel(
        const float* __restrict__ A, const float* __restrict__ B,
        const float4* __restrict__ bestp, float* __restrict__ rpart) {
    float4 h = *bestp;
    float c = h.x, s = h.y, u = h.z, v = h.w;
    float m[9];
#pragma unroll
    for (int j = 0; j < 9; ++j) m[j] = 0.f;

    int gid = blockIdx.x * RF_THREADS + threadIdx.x;   // 65536 threads
    float4 a2 = ((const float4*)A)[gid];               // 2 points
    float4 b2 = ((const float4*)B)[gid];
#pragma unroll
    for (int k = 0; k < 2; ++k) {
        float ax = k ? a2.z : a2.x, ay = k ? a2.w : a2.y;
        float bx = k ? b2.z : b2.x, by = k ? b2.w : b2.y;
        float ex = fmaf(-c, ax, fmaf(s, ay, bx - u));
        float ey = fmaf(-s, ax, fmaf(-c, ay, by - v));
        float d2 = fmaf(ex, ex, ey * ey);
        if (d2 <= THRESH2) {
            m[0] += 1.f;
            m[1] += ax; m[2] += ay; m[3] += bx; m[4] += by;
            m[5] += ax * bx; m[6] += ax * by;
            m[7] += ay * bx; m[8] += ay * by;
        }
    }
#pragma unroll
    for (int off = 32; off > 0; off >>= 1)
#pragma unroll
        for (int j = 0; j < 9; ++j) m[j] += __shfl_down(m[j], off);

    __shared__ float sred[RF_THREADS / 64][9];
    int wave = threadIdx.x >> 6, lane = threadIdx.x & 63;
    if (lane == 0)
#pragma unroll
        for (int j = 0; j < 9; ++j) sred[wave][j] = m[j];
    __syncthreads();
    if (threadIdx.x == 0) {
#pragma unroll
        for (int j = 0; j < 9; ++j) {
            float t = sred[0][j] + sred[1][j] + sred[2][j] + sred[3][j];
            rpart[blockIdx.x * 16 + j] = t;
        }
    }
}

// Kernel 6: reduce 256 refit partials (one wave, 4 rows/lane) + finalize E_final.
__global__ void finalize_kernel(const float* __restrict__ rpart, float* __restrict__ out) {
    int lane = threadIdx.x;      // 64 threads = 1 wave
    float m[9];
#pragma unroll
    for (int j = 0; j < 9; ++j) m[j] = 0.f;
#pragma unroll
    for (int k = 0; k < 4; ++k)
#pragma unroll
        for (int j = 0; j < 9; ++j) m[j] += rpart[(lane + 64 * k) * 16 + j];
#pragma unroll
    for (int off = 32; off > 0; off >>= 1)
#pragma unroll
        for (int j = 0; j < 9; ++j) m[j] += __shfl_down(m[j], off);

    if (lane == 0) {
        float ws = fmaxf(m[0], 1e-8f);
        float cAx = m[1] / ws, cAy = m[2] / ws;
        float cBx = m[3] / ws, cBy = m[4] / ws;
        float sxx = (m[5] - ws * cAx * cBx) + (m[8] - ws * cAy * cBy);
        float sxy = (m[6] - ws * cAx * cBy) - (m[7] - ws * cAy * cBx);
        float rot = atan2f(sxy, sxx);
        float s, c;
        sincosf(rot, &s, &c);
        float u = cBx - (c * cAx - s * cAy);
        float v = cBy - (s * cAx + c * cAy);
        out[0] = c;   out[1] = -s;  out[2] = u;
        out[3] = s;   out[4] = c;   out[5] = v;
        out[6] = 0.f; out[7] = 0.f; out[8] = 1.f;
    }
}

extern "C" void kernel_launch(void* const* d_in, const int* in_sizes, int n_in,
                              void* d_out, int out_size, void* d_ws, size_t ws_size,
                              hipStream_t stream) {
    const float* A  = (const float*)d_in[0];   // pstA [1,N,2]
    const float* B  = (const float*)d_in[1];   // pstB [1,N,2]
    const int* sidx = (const int*)d_in[2];     // subset_idx [EPOCHS,5]
    float* out = (float*)d_out;

    char* ws = (char*)d_ws;
    float4*        H        = (float4*)(ws + OFF_H);
    unsigned char* partial  = (unsigned char*)(ws + OFF_PARTIAL);
    int*           partial2 = (int*)(ws + OFF_PARTIAL2);
    float4*        best     = (float4*)(ws + OFF_BEST);
    float*         rpart    = (float*)(ws + OFF_RPART);

    hypo_kernel<<<4, 256, 0, stream>>>(A, B, sidx, H);
    score_kernel<<<SC_BLOCKS, SC_NT, 0, stream>>>(A, B, H, partial);
    reduce_counts_kernel<<<32, 256, 0, stream>>>(partial, partial2);
    argmax_kernel<<<1, 256, 0, stream>>>(partial2, H, out, best);
    refit_kernel<<<RF_BLOCKS, RF_THREADS, 0, stream>>>(A, B, best, rpart);
    finalize_kernel<<<1, 64, 0, stream>>>(rpart, out);
}

// Round 9
// 103.372 us; speedup vs baseline: 4.0631x; 1.4995x over previous
//
#include <hip/hip_runtime.h>
#include <math.h>

#define N_PTS   131072
#define EPOCHS  1000
#define EPAD    1024
#define THRESH2 100.0f   // dis <= 10  <=>  dis^2 <= 100

#define SC_BLOCKS  1024
#define SC_NT      256                     // 4 hyps per thread, packed u32 out
#define SC_PTS     (N_PTS / SC_BLOCKS)     // 128 points per block

#define RG         16                      // reduce groups
#define RGB        (SC_BLOCKS / RG)        // 64 block-rows per group

#define RF_BLOCKS  256
#define RF_THREADS 256                     // 2 points (1 float4) per thread

// ---------------- workspace layout (bytes) ----------------
// H         float4[1024]         @ 0         (16384)
// partial32 uint[1024][256]      @ 16384     (1048576) -> 1064960
// p2        uint2[16][256]       @ 1064960   (32768)   -> 1097728
// best      float4               @ 1097728   (16)      -> 1097744
// rpart     float[256][16]       @ 1097744   (16384)   -> 1114128 (proven size)
#define OFF_H        0
#define OFF_PARTIAL  16384
#define OFF_P2       1064960
#define OFF_BEST     1097728
#define OFF_RPART    1097744

// Kernel 1: one thread per epoch — 5-point rigid fit.
__global__ void hypo_kernel(const float* __restrict__ A, const float* __restrict__ B,
                            const int* __restrict__ idx, float4* __restrict__ H) {
    int e = blockIdx.x * blockDim.x + threadIdx.x;
    if (e >= EPOCHS) return;

    float ax[5], ay[5], bx[5], by[5];
    float cAx = 0.f, cAy = 0.f, cBx = 0.f, cBy = 0.f;
#pragma unroll
    for (int j = 0; j < 5; ++j) {
        int p = idx[e * 5 + j];
        ax[j] = A[2 * p];     ay[j] = A[2 * p + 1];
        bx[j] = B[2 * p];     by[j] = B[2 * p + 1];
        cAx += ax[j]; cAy += ay[j];
        cBx += bx[j]; cBy += by[j];
    }
    cAx *= 0.2f; cAy *= 0.2f; cBx *= 0.2f; cBy *= 0.2f;

    float sxx = 0.f, sxy = 0.f;
#pragma unroll
    for (int j = 0; j < 5; ++j) {
        float a0x = ax[j] - cAx, a0y = ay[j] - cAy;
        float b0x = bx[j] - cBx, b0y = by[j] - cBy;
        sxx += a0x * b0x + a0y * b0y;
        sxy += a0x * b0y - a0y * b0x;
    }
    float rot = atan2f(sxy, sxx);
    float s, c;
    sincosf(rot, &s, &c);
    float u = cBx - (c * cAx - s * cAy);
    float v = cBy - (s * cAx + c * cAy);
    H[e] = make_float4(c, s, u, v);
}

// Kernel 2: scoring. Block = 128-point LDS tile, thread = 4 hypotheses
// (tid, tid+256, tid+512, tid+768); counts packed into ONE u32 dword store
// (byte q = hyp group q) -> coalesced full-line writes, no RMW amplification.
#define EVAL(h, cnt)                                                        \
    {                                                                       \
        float ex = fmaf(-(h).x, p.x, fmaf((h).y, p.y, p.z - (h).z));        \
        float ey = fmaf(-(h).y, p.x, fmaf(-(h).x, p.y, p.w - (h).w));       \
        float d2 = fmaf(ex, ex, ey * ey);                                   \
        cnt += (d2 <= THRESH2) ? 1u : 0u;                                   \
    }

__global__ __launch_bounds__(SC_NT) void score_kernel(
        const float* __restrict__ A, const float* __restrict__ B,
        const float4* __restrict__ H, unsigned int* __restrict__ partial32) {
    __shared__ float4 pts[SC_PTS];         // 2 KB: (ax,ay,bx,by) per point
    int tid = threadIdx.x;
    int bid = blockIdx.x;

    if (tid < SC_PTS) {
        float2 a = ((const float2*)A)[bid * SC_PTS + tid];
        float2 b = ((const float2*)B)[bid * SC_PTS + tid];
        pts[tid] = make_float4(a.x, a.y, b.x, b.y);
    }
    float4 h0 = H[tid];
    float4 h1 = H[tid + 256];
    float4 h2 = H[tid + 512];
    float4 h3 = H[tid + 768];
    __syncthreads();

    unsigned int c0 = 0, c1 = 0, c2 = 0, c3 = 0;
#pragma unroll 4
    for (int k = 0; k < SC_PTS; ++k) {
        float4 p = pts[k];                 // uniform addr -> LDS broadcast
        EVAL(h0, c0); EVAL(h1, c1); EVAL(h2, c2); EVAL(h3, c3);
    }
    // counts <= 128 each; pack 4 bytes -> one dword per lane (coalesced 1KB/wave)
    partial32[bid * 256 + tid] = c0 | (c1 << 8) | (c2 << 16) | (c3 << 24);
}

// Kernel 3: stage-A reduction with 16-bit SWAR. Group g sums 64 block-rows.
// lo accumulates bytes 0,2 (hyp groups 0,2) in 16-bit fields; hi bytes 1,3.
// Max field value 64*128 = 8192 < 65536 -> no carry between fields.
__global__ void reduce_counts_kernel(const unsigned int* __restrict__ partial32,
                                     uint2* __restrict__ p2) {
    int gid = blockIdx.x * blockDim.x + threadIdx.x;   // 16*256 = 4096 threads
    int t = gid & 255;
    int g = gid >> 8;                                  // 0..15
    unsigned int lo = 0, hi = 0;
    int base = g * RGB;
#pragma unroll 8
    for (int k = 0; k < RGB; ++k) {
        unsigned int x = partial32[(base + k) * 256 + t];
        lo += x & 0x00FF00FFu;
        hi += (x >> 8) & 0x00FF00FFu;
    }
    p2[g * 256 + t] = make_uint2(lo, hi);
}

// Kernel 4: final count sum + argmax (first-index tie-break == jnp.argmax).
// BUGFIX (r8): unpack each group's 16-bit fields BEFORE summing — the total
// per-hyp count reaches 131072 (all points inliers) which overflows a 16-bit
// field if the packed words are summed first.
__global__ void argmax_kernel(const uint2* __restrict__ p2, const float4* __restrict__ H,
                              float* __restrict__ out, float4* __restrict__ best) {
    __shared__ int scnt[256];
    __shared__ int sidx[256];
    int tid = threadIdx.x;
    int cv[4] = {0, 0, 0, 0};          // hyps tid, tid+256, tid+512, tid+768
#pragma unroll
    for (int g = 0; g < RG; ++g) {
        uint2 w = p2[g * 256 + tid];
        cv[0] += (int)(w.x & 0xFFFFu);
        cv[2] += (int)(w.x >> 16);
        cv[1] += (int)(w.y & 0xFFFFu);
        cv[3] += (int)(w.y >> 16);
    }
    int bc = -1, bi = 0;
#pragma unroll
    for (int q = 0; q < 4; ++q) {                      // ascending e: '>' keeps first
        int e = tid + 256 * q;
        int c2 = (e < EPOCHS) ? cv[q] : -1;            // mask padded hyps
        if (c2 > bc) { bc = c2; bi = e; }
    }
    scnt[tid] = bc; sidx[tid] = bi;
    __syncthreads();
    for (int s2 = 128; s2 > 0; s2 >>= 1) {
        if (tid < s2) {
            int c2 = scnt[tid + s2], i2 = sidx[tid + s2];
            if (c2 > scnt[tid] || (c2 == scnt[tid] && i2 < sidx[tid])) {
                scnt[tid] = c2; sidx[tid] = i2;
            }
        }
        __syncthreads();
    }
    if (tid == 0) {
        float4 h = H[sidx[0]];
        *best = h;
        out[9]  = h.x;  out[10] = -h.y; out[11] = h.z;
        out[12] = h.y;  out[13] = h.x;  out[14] = h.w;
        out[15] = 0.f;  out[16] = 0.f;  out[17] = 1.f;
    }
}

// Kernel 5: refit raw moments; 2 points (one float4) per thread; no atomics.
//  moments: 0=Sw 1=SxA 2=SyA 3=SxB 4=SyB 5=SxAxB 6=SxAyB 7=SyAxB 8=SyAyB
__global__ __launch_bounds__(RF_THREADS) void refit_kernel(
        const float* __restrict__ A, const float* __restrict__ B,
        const float4* __restrict__ bestp, float* __restrict__ rpart) {
    float4 h = *bestp;
    float c = h.x, s = h.y, u = h.z, v = h.w;
    float m[9];
#pragma unroll
    for (int j = 0; j < 9; ++j) m[j] = 0.f;

    int gid = blockIdx.x * RF_THREADS + threadIdx.x;   // 65536 threads
    float4 a2 = ((const float4*)A)[gid];               // 2 points
    float4 b2 = ((const float4*)B)[gid];
#pragma unroll
    for (int k = 0; k < 2; ++k) {
        float ax = k ? a2.z : a2.x, ay = k ? a2.w : a2.y;
        float bx = k ? b2.z : b2.x, by = k ? b2.w : b2.y;
        float ex = fmaf(-c, ax, fmaf(s, ay, bx - u));
        float ey = fmaf(-s, ax, fmaf(-c, ay, by - v));
        float d2 = fmaf(ex, ex, ey * ey);
        if (d2 <= THRESH2) {
            m[0] += 1.f;
            m[1] += ax; m[2] += ay; m[3] += bx; m[4] += by;
            m[5] += ax * bx; m[6] += ax * by;
            m[7] += ay * bx; m[8] += ay * by;
        }
    }
#pragma unroll
    for (int off = 32; off > 0; off >>= 1)
#pragma unroll
        for (int j = 0; j < 9; ++j) m[j] += __shfl_down(m[j], off);

    __shared__ float sred[RF_THREADS / 64][9];
    int wave = threadIdx.x >> 6, lane = threadIdx.x & 63;
    if (lane == 0)
#pragma unroll
        for (int j = 0; j < 9; ++j) sred[wave][j] = m[j];
    __syncthreads();
    if (threadIdx.x == 0) {
#pragma unroll
        for (int j = 0; j < 9; ++j) {
            float t = sred[0][j] + sred[1][j] + sred[2][j] + sred[3][j];
            rpart[blockIdx.x * 16 + j] = t;
        }
    }
}

// Kernel 6: reduce 256 refit partials (one wave, 4 rows/lane) + finalize E_final.
__global__ void finalize_kernel(const float* __restrict__ rpart, float* __restrict__ out) {
    int lane = threadIdx.x;      // 64 threads = 1 wave
    float m[9];
#pragma unroll
    for (int j = 0; j < 9; ++j) m[j] = 0.f;
#pragma unroll
    for (int k = 0; k < 4; ++k)
#pragma unroll
        for (int j = 0; j < 9; ++j) m[j] += rpart[(lane + 64 * k) * 16 + j];
#pragma unroll
    for (int off = 32; off > 0; off >>= 1)
#pragma unroll
        for (int j = 0; j < 9; ++j) m[j] += __shfl_down(m[j], off);

    if (lane == 0) {
        float ws = fmaxf(m[0], 1e-8f);
        float cAx = m[1] / ws, cAy = m[2] / ws;
        float cBx = m[3] / ws, cBy = m[4] / ws;
        float sxx = (m[5] - ws * cAx * cBx) + (m[8] - ws * cAy * cBy);
        float sxy = (m[6] - ws * cAx * cBy) - (m[7] - ws * cAy * cBx);
        float rot = atan2f(sxy, sxx);
        float s, c;
        sincosf(rot, &s, &c);
        float u = cBx - (c * cAx - s * cAy);
        float v = cBy - (s * cAx + c * cAy);
        out[0] = c;   out[1] = -s;  out[2] = u;
        out[3] = s;   out[4] = c;   out[5] = v;
        out[6] = 0.f; out[7] = 0.f; out[8] = 1.f;
    }
}

extern "C" void kernel_launch(void* const* d_in, const int* in_sizes, int n_in,
                              void* d_out, int out_size, void* d_ws, size_t ws_size,
                              hipStream_t stream) {
    const float* A  = (const float*)d_in[0];   // pstA [1,N,2]
    const float* B  = (const float*)d_in[1];   // pstB [1,N,2]
    const int* sidx = (const int*)d_in[2];     // subset_idx [EPOCHS,5]
    float* out = (float*)d_out;

    char* ws = (char*)d_ws;
    float4*       H         = (float4*)(ws + OFF_H);
    unsigned int* partial32 = (unsigned int*)(ws + OFF_PARTIAL);
    uint2*        p2        = (uint2*)(ws + OFF_P2);
    float4*       best      = (float4*)(ws + OFF_BEST);
    float*        rpart     = (float*)(ws + OFF_RPART);

    hypo_kernel<<<4, 256, 0, stream>>>(A, B, sidx, H);
    score_kernel<<<SC_BLOCKS, SC_NT, 0, stream>>>(A, B, H, partial32);
    reduce_counts_kernel<<<RG, 256, 0, stream>>>(partial32, p2);
    argmax_kernel<<<1, 256, 0, stream>>>(p2, H, out, best);
    refit_kernel<<<RF_BLOCKS, RF_THREADS, 0, stream>>>(A, B, best, rpart);
    finalize_kernel<<<1, 64, 0, stream>>>(rpart, out);
}

// Round 10
// 103.184 us; speedup vs baseline: 4.0705x; 1.0018x over previous
//
#include <hip/hip_runtime.h>
#include <math.h>

#define N_PTS   131072
#define EPOCHS  1000
#define EPAD    1024
#define THRESH2 100.0f   // dis <= 10  <=>  dis^2 <= 100

#define SC_BLOCKS  2048
#define SC_NT      256                     // 4 hyps per thread, packed u32 out
#define SC_PTS     (N_PTS / SC_BLOCKS)     // 64 points per block -> 8 blocks/CU

#define RG         16                      // reduce groups
#define RGB        (SC_BLOCKS / RG)        // 128 block-rows per group

#define RF_BLOCKS  256
#define RF_THREADS 256                     // 2 points (1 float4) per thread

// ---------------- workspace layout (bytes) ----------------
// H         float4[1024]         @ 0         (16384)
// partial32 uint[2048][256]      @ 16384     (2097152) -> 2113536
// p2        uint2[16][256]       @ 2113536   (32768)   -> 2146304
// rpart     float[256][16]       @ 2146304   (16384)   -> 2162688
#define OFF_H        0
#define OFF_PARTIAL  16384
#define OFF_P2       2113536
#define OFF_RPART    2146304

// Kernel 1: one thread per epoch — 5-point rigid fit.
__global__ void hypo_kernel(const float* __restrict__ A, const float* __restrict__ B,
                            const int* __restrict__ idx, float4* __restrict__ H) {
    int e = blockIdx.x * blockDim.x + threadIdx.x;
    if (e >= EPOCHS) return;

    float ax[5], ay[5], bx[5], by[5];
    float cAx = 0.f, cAy = 0.f, cBx = 0.f, cBy = 0.f;
#pragma unroll
    for (int j = 0; j < 5; ++j) {
        int p = idx[e * 5 + j];
        ax[j] = A[2 * p];     ay[j] = A[2 * p + 1];
        bx[j] = B[2 * p];     by[j] = B[2 * p + 1];
        cAx += ax[j]; cAy += ay[j];
        cBx += bx[j]; cBy += by[j];
    }
    cAx *= 0.2f; cAy *= 0.2f; cBx *= 0.2f; cBy *= 0.2f;

    float sxx = 0.f, sxy = 0.f;
#pragma unroll
    for (int j = 0; j < 5; ++j) {
        float a0x = ax[j] - cAx, a0y = ay[j] - cAy;
        float b0x = bx[j] - cBx, b0y = by[j] - cBy;
        sxx += a0x * b0x + a0y * b0y;
        sxy += a0x * b0y - a0y * b0x;
    }
    float rot = atan2f(sxy, sxx);
    float s, c;
    sincosf(rot, &s, &c);
    float u = cBx - (c * cAx - s * cAy);
    float v = cBy - (s * cAx + c * cAy);
    H[e] = make_float4(c, s, u, v);
}

// Kernel 2: scoring. Block = 64-point LDS tile (8 blocks/CU -> 32 waves/CU),
// thread = 4 hypotheses (tid, +256, +512, +768); 4 u8 counts packed into one
// coalesced u32 dword store (no partial-line RMW amplification).
#define EVAL(h, cnt)                                                        \
    {                                                                       \
        float ex = fmaf(-(h).x, p.x, fmaf((h).y, p.y, p.z - (h).z));        \
        float ey = fmaf(-(h).y, p.x, fmaf(-(h).x, p.y, p.w - (h).w));       \
        float d2 = fmaf(ex, ex, ey * ey);                                   \
        cnt += (d2 <= THRESH2) ? 1u : 0u;                                   \
    }

__global__ __launch_bounds__(SC_NT) void score_kernel(
        const float* __restrict__ A, const float* __restrict__ B,
        const float4* __restrict__ H, unsigned int* __restrict__ partial32) {
    __shared__ float4 pts[SC_PTS];         // 1 KB: (ax,ay,bx,by) per point
    int tid = threadIdx.x;
    int bid = blockIdx.x;

    if (tid < SC_PTS) {
        float2 a = ((const float2*)A)[bid * SC_PTS + tid];
        float2 b = ((const float2*)B)[bid * SC_PTS + tid];
        pts[tid] = make_float4(a.x, a.y, b.x, b.y);
    }
    float4 h0 = H[tid];
    float4 h1 = H[tid + 256];
    float4 h2 = H[tid + 512];
    float4 h3 = H[tid + 768];
    __syncthreads();

    unsigned int c0 = 0, c1 = 0, c2 = 0, c3 = 0;
#pragma unroll 4
    for (int k = 0; k < SC_PTS; ++k) {
        float4 p = pts[k];                 // uniform addr -> LDS broadcast
        EVAL(h0, c0); EVAL(h1, c1); EVAL(h2, c2); EVAL(h3, c3);
    }
    // counts <= 64 each; pack 4 bytes -> one dword per lane (coalesced)
    partial32[bid * 256 + tid] = c0 | (c1 << 8) | (c2 << 16) | (c3 << 24);
}

// Kernel 3: stage-A reduction with 16-bit SWAR. Group g sums 128 block-rows.
// lo accumulates bytes 0,2 (hyp groups 0,2) in 16-bit fields; hi bytes 1,3.
// Max field value 128*64 = 8192 < 65536 -> no carry between fields.
__global__ void reduce_counts_kernel(const unsigned int* __restrict__ partial32,
                                     uint2* __restrict__ p2) {
    int gid = blockIdx.x * blockDim.x + threadIdx.x;   // 16*256 = 4096 threads
    int t = gid & 255;
    int g = gid >> 8;                                  // 0..15
    unsigned int lo = 0, hi = 0;
    int base = g * RGB;
#pragma unroll 8
    for (int k = 0; k < RGB; ++k) {
        unsigned int x = partial32[(base + k) * 256 + t];
        lo += x & 0x00FF00FFu;
        hi += (x >> 8) & 0x00FF00FFu;
    }
    p2[g * 256 + t] = make_uint2(lo, hi);
}

// Kernel 4: fused argmax + refit. Every block redundantly computes the argmax
// from p2 (deterministic integer sums -> identical winner everywhere; 16-bit
// fields unpacked BEFORE summing, r8 overflow lesson). Block 0 writes E_best.
// Then each block accumulates its refit moments -> rpart.
//  moments: 0=Sw 1=SxA 2=SyA 3=SxB 4=SyB 5=SxAxB 6=SxAyB 7=SyAxB 8=SyAyB
__global__ __launch_bounds__(RF_THREADS) void refit_argmax_kernel(
        const float* __restrict__ A, const float* __restrict__ B,
        const uint2* __restrict__ p2, const float4* __restrict__ H,
        float* __restrict__ out, float* __restrict__ rpart) {
    __shared__ int scnt[256];
    __shared__ int sidx[256];
    int tid = threadIdx.x;
    int bid = blockIdx.x;

    // --- argmax (first-index tie-break == jnp.argmax) ---
    int cv[4] = {0, 0, 0, 0};              // hyps tid, tid+256, tid+512, tid+768
#pragma unroll
    for (int g = 0; g < RG; ++g) {
        uint2 w = p2[g * 256 + tid];
        cv[0] += (int)(w.x & 0xFFFFu);
        cv[2] += (int)(w.x >> 16);
        cv[1] += (int)(w.y & 0xFFFFu);
        cv[3] += (int)(w.y >> 16);
    }
    int bc = -1, bi = 0;
#pragma unroll
    for (int q = 0; q < 4; ++q) {          // ascending e: '>' keeps first max
        int e = tid + 256 * q;
        int c2 = (e < EPOCHS) ? cv[q] : -1;
        if (c2 > bc) { bc = c2; bi = e; }
    }
    scnt[tid] = bc; sidx[tid] = bi;
    __syncthreads();
    for (int s2 = 128; s2 > 0; s2 >>= 1) {
        if (tid < s2) {
            int c2 = scnt[tid + s2], i2 = sidx[tid + s2];
            if (c2 > scnt[tid] || (c2 == scnt[tid] && i2 < sidx[tid])) {
                scnt[tid] = c2; sidx[tid] = i2;
            }
        }
        __syncthreads();
    }
    float4 h = H[sidx[0]];                 // broadcast winner (all blocks agree)
    if (bid == 0 && tid == 0) {
        out[9]  = h.x;  out[10] = -h.y; out[11] = h.z;
        out[12] = h.y;  out[13] = h.x;  out[14] = h.w;
        out[15] = 0.f;  out[16] = 0.f;  out[17] = 1.f;
    }

    // --- refit moments (2 points / thread) ---
    float c = h.x, s = h.y, u = h.z, v = h.w;
    float m[9];
#pragma unroll
    for (int j = 0; j < 9; ++j) m[j] = 0.f;

    int gid = bid * RF_THREADS + tid;      // 65536 threads
    float4 a2 = ((const float4*)A)[gid];   // 2 points
    float4 b2 = ((const float4*)B)[gid];
#pragma unroll
    for (int k = 0; k < 2; ++k) {
        float ax = k ? a2.z : a2.x, ay = k ? a2.w : a2.y;
        float bx = k ? b2.z : b2.x, by = k ? b2.w : b2.y;
        float ex = fmaf(-c, ax, fmaf(s, ay, bx - u));
        float ey = fmaf(-s, ax, fmaf(-c, ay, by - v));
        float d2 = fmaf(ex, ex, ey * ey);
        if (d2 <= THRESH2) {
            m[0] += 1.f;
            m[1] += ax; m[2] += ay; m[3] += bx; m[4] += by;
            m[5] += ax * bx; m[6] += ax * by;
            m[7] += ay * bx; m[8] += ay * by;
        }
    }
#pragma unroll
    for (int off = 32; off > 0; off >>= 1)
#pragma unroll
        for (int j = 0; j < 9; ++j) m[j] += __shfl_down(m[j], off);

    __shared__ float sred[RF_THREADS / 64][9];
    int wave = tid >> 6, lane = tid & 63;
    __syncthreads();                        // reuse of LDS region is safe anyway;
    if (lane == 0)                          // sync orders argmax reads vs nothing
#pragma unroll
        for (int j = 0; j < 9; ++j) sred[wave][j] = m[j];
    __syncthreads();
    if (tid == 0) {
#pragma unroll
        for (int j = 0; j < 9; ++j) {
            float t = sred[0][j] + sred[1][j] + sred[2][j] + sred[3][j];
            rpart[bid * 16 + j] = t;
        }
    }
}

// Kernel 5: reduce 256 refit partials (one wave, 4 rows/lane) + finalize E_final.
__global__ void finalize_kernel(const float* __restrict__ rpart, float* __restrict__ out) {
    int lane = threadIdx.x;      // 64 threads = 1 wave
    float m[9];
#pragma unroll
    for (int j = 0; j < 9; ++j) m[j] = 0.f;
#pragma unroll
    for (int k = 0; k < 4; ++k)
#pragma unroll
        for (int j = 0; j < 9; ++j) m[j] += rpart[(lane + 64 * k) * 16 + j];
#pragma unroll
    for (int off = 32; off > 0; off >>= 1)
#pragma unroll
        for (int j = 0; j < 9; ++j) m[j] += __shfl_down(m[j], off);

    if (lane == 0) {
        float ws = fmaxf(m[0], 1e-8f);
        float cAx = m[1] / ws, cAy = m[2] / ws;
        float cBx = m[3] / ws, cBy = m[4] / ws;
        float sxx = (m[5] - ws * cAx * cBx) + (m[8] - ws * cAy * cBy);
        float sxy = (m[6] - ws * cAx * cBy) - (m[7] - ws * cAy * cBx);
        float rot = atan2f(sxy, sxx);
        float s, c;
        sincosf(rot, &s, &c);
        float u = cBx - (c * cAx - s * cAy);
        float v = cBy - (s * cAx + c * cAy);
        out[0] = c;   out[1] = -s;  out[2] = u;
        out[3] = s;   out[4] = c;   out[5] = v;
        out[6] = 0.f; out[7] = 0.f; out[8] = 1.f;
    }
}

extern "C" void kernel_launch(void* const* d_in, const int* in_sizes, int n_in,
                              void* d_out, int out_size, void* d_ws, size_t ws_size,
                              hipStream_t stream) {
    const float* A  = (const float*)d_in[0];   // pstA [1,N,2]
    const float* B  = (const float*)d_in[1];   // pstB [1,N,2]
    const int* sidx = (const int*)d_in[2];     // subset_idx [EPOCHS,5]
    float* out = (float*)d_out;

    char* ws = (char*)d_ws;
    float4*       H         = (float4*)(ws + OFF_H);
    unsigned int* partial32 = (unsigned int*)(ws + OFF_PARTIAL);
    uint2*        p2        = (uint2*)(ws + OFF_P2);
    float*        rpart     = (float*)(ws + OFF_RPART);

    hypo_kernel<<<4, 256, 0, stream>>>(A, B, sidx, H);
    score_kernel<<<SC_BLOCKS, SC_NT, 0, stream>>>(A, B, H, partial32);
    reduce_counts_kernel<<<RG, 256, 0, stream>>>(partial32, p2);
    refit_argmax_kernel<<<RF_BLOCKS, RF_THREADS, 0, stream>>>(A, B, p2, H, out, rpart);
    finalize_kernel<<<1, 64, 0, stream>>>(rpart, out);
}